// Round 1
// baseline (412.037 us; speedup 1.0000x reference)
//
#include <hip/hip_runtime.h>
#include <hip/hip_bf16.h>

// Problem constants (B=4, M=4096, DM=1024, H=16, HD=64, SEG=128, DIL=2, BLOCK_M=64)
#define BB 4
#define MM 4096
#define DM 1024
#define NH 16
#define HDIM 64
#define SEGSZ 128
#define NSEG 32          // M/SEG
#define TK 64            // SEG/DIL keys per segment
#define NBLK 2           // SEG/BLOCK_M
#define ROWS (BB*MM)     // 16384
#define QKVC (3*DM)      // 3072

typedef __attribute__((ext_vector_type(8))) short bf16x8;
typedef __attribute__((ext_vector_type(4))) float f32x4;

__device__ inline unsigned short f2bf(float f) {
  __hip_bfloat16 h = __float2bfloat16(f);
  return *reinterpret_cast<unsigned short*>(&h);
}

__device__ inline void bf8tof(uint4 v, float* o) {
  o[0] = __uint_as_float(v.x << 16); o[1] = __uint_as_float(v.x & 0xffff0000u);
  o[2] = __uint_as_float(v.y << 16); o[3] = __uint_as_float(v.y & 0xffff0000u);
  o[4] = __uint_as_float(v.z << 16); o[5] = __uint_as_float(v.z & 0xffff0000u);
  o[6] = __uint_as_float(v.w << 16); o[7] = __uint_as_float(v.w & 0xffff0000u);
}

// ---------------- fp32 -> bf16 convert ----------------
__global__ __launch_bounds__(256) void cvt_bf16(const float4* __restrict__ in,
                                                ushort4* __restrict__ out, int n4) {
  int i = blockIdx.x * 256 + threadIdx.x;
  if (i >= n4) return;
  float4 v = in[i];
  ushort4 o;
  o.x = f2bf(v.x); o.y = f2bf(v.y); o.z = f2bf(v.z); o.w = f2bf(v.w);
  out[i] = o;
}

// ---------------- NT GEMM: C[m][n] = sum_k A[m,k]*B[n,k], bf16 in, fp32 acc ----------------
// 128x128 tile, BK=32, 256 threads (4 waves, each 64x64 via 4x4 mfma_16x16x32_bf16)
template<int OUT_BF16>
__global__ __launch_bounds__(256) void gemm_nt(const ushort* __restrict__ A,
                                               const ushort* __restrict__ B,
                                               void* __restrict__ Cv,
                                               int M, int N, int K) {
  constexpr int LDK = 40;  // 32 + 8 pad (bf16 elems) -> ds_read_b128 2-way only
  __shared__ __align__(16) ushort sA[128 * LDK];
  __shared__ __align__(16) ushort sB[128 * LDK];
  const int tid  = threadIdx.x;
  const int lane = tid & 63;
  const int wave = tid >> 6;
  const int row0 = blockIdx.x * 128;
  const int col0 = blockIdx.y * 128;
  const int wr = (wave >> 1) * 64;
  const int wc = (wave & 1) * 64;
  const int m16 = lane & 15;
  const int quad = lane >> 4;

  f32x4 acc[4][4] = {};

  const int c0 = tid, c1 = tid + 256;        // 512 chunks of 8 bf16 per tile
  const int ar0 = c0 >> 2, ak0 = (c0 & 3) * 8;
  const int ar1 = c1 >> 2, ak1 = (c1 & 3) * 8;

  const ushort* Ab = A + (size_t)row0 * K;
  const ushort* Bb = B + (size_t)col0 * K;

  for (int kt = 0; kt < K; kt += 32) {
    uint4 va0 = *(const uint4*)(Ab + (size_t)ar0 * K + kt + ak0);
    uint4 va1 = *(const uint4*)(Ab + (size_t)ar1 * K + kt + ak1);
    uint4 vb0 = *(const uint4*)(Bb + (size_t)ar0 * K + kt + ak0);
    uint4 vb1 = *(const uint4*)(Bb + (size_t)ar1 * K + kt + ak1);
    __syncthreads();
    *(uint4*)(sA + ar0 * LDK + ak0) = va0;
    *(uint4*)(sA + ar1 * LDK + ak1) = va1;
    *(uint4*)(sB + ar0 * LDK + ak0) = vb0;
    *(uint4*)(sB + ar1 * LDK + ak1) = vb1;
    __syncthreads();

    bf16x8 af[4], bfr[4];
#pragma unroll
    for (int i = 0; i < 4; ++i) {
      af[i]  = *(const bf16x8*)(sA + (wr + i * 16 + m16) * LDK + quad * 8);
      bfr[i] = *(const bf16x8*)(sB + (wc + i * 16 + m16) * LDK + quad * 8);
    }
#pragma unroll
    for (int i = 0; i < 4; ++i)
#pragma unroll
      for (int j = 0; j < 4; ++j)
        acc[i][j] = __builtin_amdgcn_mfma_f32_16x16x32_bf16(af[i], bfr[j], acc[i][j], 0, 0, 0);
  }

  // C/D layout: col = lane&15, row = (lane>>4)*4 + r  [verified m89/m91]
#pragma unroll
  for (int i = 0; i < 4; ++i) {
#pragma unroll
    for (int r = 0; r < 4; ++r) {
      int row = row0 + wr + i * 16 + quad * 4 + r;
#pragma unroll
      for (int j = 0; j < 4; ++j) {
        int col = col0 + wc + j * 16 + m16;
        float v = acc[i][j][r];
        if (OUT_BF16) ((ushort*)Cv)[(size_t)row * N + col] = f2bf(v);
        else          ((float*)Cv)[(size_t)row * N + col] = v;
      }
    }
  }
}

// ---------------- fused hilbert attention (faithful non-softmax quirk) ----------------
// one workgroup (256 thr) per (b,h,s,nb): 64 queries x 64 dilated keys x 64 dims
__global__ __launch_bounds__(256) void attn_kernel(const ushort* __restrict__ qkv,  // [ROWS][3072] bf16
                                                   const int* __restrict__ hmap,    // [M]
                                                   ushort* __restrict__ out)        // [ROWS][1024] bf16
{
  __shared__ __align__(16) float  sQ[64 * 65];    // fp32, scalar-broadcast reads
  __shared__ __align__(16) float  sKT[64 * 68];   // transposed [d][t], float4 reads along t
  __shared__ __align__(16) ushort sVb[64 * 72];   // bf16 [t][d], uint2 reads along d
  __shared__ __align__(16) float  sW[64 * 65];    // scores -> weights
  __shared__ float sC[64];                        // per-key max over query block
  __shared__ float sDenR[64];                     // 1/den per query
  __shared__ float sPart[256];

  const int bid = blockIdx.x;
  const int nb = bid & 1;
  const int s  = (bid >> 1) & 31;
  const int h  = (bid >> 6) & 15;
  const int b  = bid >> 10;
  const int tid = threadIdx.x;

  // ---- stage Q (scaled fp32), K^T (fp32), V (bf16) ----
  {
    const int r  = tid >> 2;          // 0..63
    const int cq = (tid & 3) * 16;    // col start (16 elems = 2 chunks)
    const int p  = s * SEGSZ + nb * 64 + r;
    const int gq = b * MM + hmap[p];
    const int gk = b * MM + hmap[s * SEGSZ + 2 * r];
    const ushort* qrow = qkv + (size_t)gq * QKVC + h * HDIM + cq;
    const ushort* krow = qkv + (size_t)gk * QKVC + DM + h * HDIM + cq;
    const ushort* vrow = qkv + (size_t)gk * QKVC + 2 * DM + h * HDIM + cq;
    uint4 q0 = ((const uint4*)qrow)[0], q1 = ((const uint4*)qrow)[1];
    uint4 k0 = ((const uint4*)krow)[0], k1 = ((const uint4*)krow)[1];
    uint4 v0 = ((const uint4*)vrow)[0], v1 = ((const uint4*)vrow)[1];
    float fq[16], fk[16];
    bf8tof(q0, fq); bf8tof(q1, fq + 8);
    bf8tof(k0, fk); bf8tof(k1, fk + 8);
#pragma unroll
    for (int u = 0; u < 16; ++u) {
      sQ[r * 65 + cq + u] = fq[u] * 0.125f;   // HD^-0.5
      sKT[(cq + u) * 68 + r] = fk[u];
    }
    *(uint4*)(sVb + r * 72 + cq)     = v0;    // raw bf16 copy
    *(uint4*)(sVb + r * 72 + cq + 8) = v1;
  }
  __syncthreads();

  const int qi0 = (tid >> 4) * 4;
  const int t0  = (tid & 15) * 4;

  // ---- scores: 4x4 register tile per thread ----
  {
    float acc[4][4] = {};
    for (int d = 0; d < 64; ++d) {
      float4 kv = *(const float4*)(sKT + d * 68 + t0);
#pragma unroll
      for (int i = 0; i < 4; ++i) {
        float q = sQ[(qi0 + i) * 65 + d];
        acc[i][0] += q * kv.x; acc[i][1] += q * kv.y;
        acc[i][2] += q * kv.z; acc[i][3] += q * kv.w;
      }
    }
#pragma unroll
    for (int i = 0; i < 4; ++i) {
      float* wr = sW + (qi0 + i) * 65 + t0;
      wr[0] = acc[i][0]; wr[1] = acc[i][1]; wr[2] = acc[i][2]; wr[3] = acc[i][3];
    }
  }
  __syncthreads();

  // ---- per-KEY max over the 64-query block (faithful quirk) ----
  if (tid < 64) {
    float m = -1e30f;
    for (int qi = 0; qi < 64; ++qi) m = fmaxf(m, sW[qi * 65 + tid]);
    sC[tid] = m;
  }
  __syncthreads();

  // ---- w = exp(score - c[t]); per-row partial sums ----
  {
    const int qi  = tid >> 2;
    const int tt0 = (tid & 3) * 16;
    float part = 0.f;
#pragma unroll
    for (int u = 0; u < 16; ++u) {
      float w = __expf(sW[qi * 65 + tt0 + u] - sC[tt0 + u]);
      sW[qi * 65 + tt0 + u] = w;
      part += w;
    }
    sPart[qi * 4 + (tid & 3)] = part;
  }
  __syncthreads();
  if (tid < 64)
    sDenR[tid] = 1.0f / (1e-10f + sPart[tid * 4] + sPart[tid * 4 + 1] +
                         sPart[tid * 4 + 2] + sPart[tid * 4 + 3]);
  __syncthreads();

  // ---- num = w @ V, divide, store at LINEAR positions ----
  {
    const int d0 = t0;
    float acc[4][4] = {};
    for (int t = 0; t < 64; ++t) {
      uint2 vv = *(const uint2*)(sVb + t * 72 + d0);
      float v0 = __uint_as_float(vv.x << 16);
      float v1 = __uint_as_float(vv.x & 0xffff0000u);
      float v2 = __uint_as_float(vv.y << 16);
      float v3 = __uint_as_float(vv.y & 0xffff0000u);
#pragma unroll
      for (int i = 0; i < 4; ++i) {
        float w = sW[(qi0 + i) * 65 + t];
        acc[i][0] += w * v0; acc[i][1] += w * v1;
        acc[i][2] += w * v2; acc[i][3] += w * v3;
      }
    }
#pragma unroll
    for (int i = 0; i < 4; ++i) {
      float rd = sDenR[qi0 + i];
      int prow = b * MM + s * SEGSZ + nb * 64 + qi0 + i;
      ushort4 o;
      o.x = f2bf(acc[i][0] * rd); o.y = f2bf(acc[i][1] * rd);
      o.z = f2bf(acc[i][2] * rd); o.w = f2bf(acc[i][3] * rd);
      *(ushort4*)(out + (size_t)prow * DM + h * HDIM + d0) = o;
    }
  }
}

// ---------------- launch ----------------
extern "C" void kernel_launch(void* const* d_in, const int* in_sizes, int n_in,
                              void* d_out, int out_size, void* d_ws, size_t ws_size,
                              hipStream_t stream) {
  const float* x    = (const float*)d_in[0];   // [B,M,DM]
  const float* wqkv = (const float*)d_in[1];   // [3DM,DM]
  const float* wout = (const float*)d_in[2];   // [DM,DM]
  const int*   hmap = (const int*)d_in[3];     // [M]
  float* outp = (float*)d_out;                 // [B,M,DM] fp32

  ushort* xbf    = (ushort*)d_ws;                          // ROWS*DM
  ushort* wqkvbf = xbf + (size_t)ROWS * DM;                // QKVC*DM
  ushort* woutbf = wqkvbf + (size_t)QKVC * DM;             // DM*DM
  ushort* qkv    = woutbf + (size_t)DM * DM;               // ROWS*QKVC
  ushort* attn   = qkv + (size_t)ROWS * QKVC;              // ROWS*DM

  const int nx = ROWS * DM, nw1 = QKVC * DM, nw2 = DM * DM;
  cvt_bf16<<<(nx / 4 + 255) / 256, 256, 0, stream>>>((const float4*)x, (ushort4*)xbf, nx / 4);
  cvt_bf16<<<(nw1 / 4 + 255) / 256, 256, 0, stream>>>((const float4*)wqkv, (ushort4*)wqkvbf, nw1 / 4);
  cvt_bf16<<<(nw2 / 4 + 255) / 256, 256, 0, stream>>>((const float4*)wout, (ushort4*)woutbf, nw2 / 4);

  // qkv = x @ Wqkv^T   (NT)
  gemm_nt<1><<<dim3(ROWS / 128, QKVC / 128), 256, 0, stream>>>(xbf, wqkvbf, qkv, ROWS, QKVC, DM);

  // fused hilbert attention
  attn_kernel<<<BB * NH * NSEG * NBLK, 256, 0, stream>>>(qkv, hmap, attn);

  // out = attn @ Wout^T  (NT, fp32 out)
  gemm_nt<0><<<dim3(ROWS / 128, DM / 128), 256, 0, stream>>>(attn, woutbf, outp, ROWS, DM, DM);
}

// Round 2
// 348.165 us; speedup vs baseline: 1.1835x; 1.1835x over previous
//
#include <hip/hip_runtime.h>
#include <hip/hip_bf16.h>

// Problem constants (B=4, M=4096, DM=1024, H=16, HD=64, SEG=128, DIL=2, BLOCK_M=64)
#define BB 4
#define MM 4096
#define DM 1024
#define NH 16
#define HDIM 64
#define SEGSZ 128
#define NSEG 32
#define ROWS (BB*MM)     // 16384
#define QKVC (3*DM)      // 3072

typedef __attribute__((ext_vector_type(8))) short bf16x8;
typedef __attribute__((ext_vector_type(4))) float f32x4;

__device__ inline unsigned short f2bf(float f) {
  __hip_bfloat16 h = __float2bfloat16(f);
  return *reinterpret_cast<unsigned short*>(&h);
}

// async global->LDS, 16B per lane; LDS dest = wave-uniform base + lane*16
__device__ __forceinline__ void gld16(const ushort* g, ushort* l) {
  __builtin_amdgcn_global_load_lds(
      (const __attribute__((address_space(1))) unsigned int*)g,
      (__attribute__((address_space(3))) unsigned int*)l,
      16, 0, 0);
}

// ---------------- fp32 -> bf16 convert ----------------
__global__ __launch_bounds__(256) void cvt_bf16(const float4* __restrict__ in,
                                                ushort4* __restrict__ out, int n4) {
  int i = blockIdx.x * 256 + threadIdx.x;
  if (i >= n4) return;
  float4 v = in[i];
  ushort4 o;
  o.x = f2bf(v.x); o.y = f2bf(v.y); o.z = f2bf(v.z); o.w = f2bf(v.w);
  out[i] = o;
}

// ---------------- NT GEMM (m97 structure): C[m][n] = sum_k A[m,k]*B[n,k] ----------------
// 128x128 tile, BK=32, 256 threads, global_load_lds width=16, unpadded LDS
template<int OUT_BF16>
__global__ __launch_bounds__(256) void gemm_nt(const ushort* __restrict__ A,
                                               const ushort* __restrict__ B,
                                               void* __restrict__ Cv,
                                               int M, int N, int K) {
  __shared__ __align__(16) ushort sA[128 * 32];   // unpadded: required by global_load_lds
  __shared__ __align__(16) ushort sB[128 * 32];
  const int tid  = threadIdx.x;
  const int lane = tid & 63;
  const int wave = tid >> 6;
  const int row0 = blockIdx.x * 128;
  const int col0 = blockIdx.y * 128;
  const int wr = (wave >> 1) * 64;
  const int wc = (wave & 1) * 64;
  const int m16 = lane & 15;
  const int quad = lane >> 4;

  f32x4 acc[4][4] = {};

  // chunk = 16B = 8 bf16; tile = 512 chunks; call0 covers chunks [wave*64, +64), call1 +256
  const int ch0 = wave * 64 + lane;
  const int ch1 = 256 + wave * 64 + lane;
  const int r0 = ch0 >> 2, k0 = (ch0 & 3) * 8;
  const int r1 = ch1 >> 2, k1 = (ch1 & 3) * 8;

  const ushort* Ab = A + (size_t)row0 * K;
  const ushort* Bb = B + (size_t)col0 * K;
  ushort* sA0 = sA + wave * 512;
  ushort* sA1 = sA + 2048 + wave * 512;
  ushort* sB0 = sB + wave * 512;
  ushort* sB1 = sB + 2048 + wave * 512;

  for (int kt = 0; kt < K; kt += 32) {
    __syncthreads();   // prior iteration's ds_reads done before overwrite
    gld16(Ab + (size_t)r0 * K + kt + k0, sA0);
    gld16(Ab + (size_t)r1 * K + kt + k1, sA1);
    gld16(Bb + (size_t)r0 * K + kt + k0, sB0);
    gld16(Bb + (size_t)r1 * K + kt + k1, sB1);
    __syncthreads();   // compiler emits vmcnt(0) drain before barrier -> data visible

    bf16x8 af[4], bfr[4];
#pragma unroll
    for (int i = 0; i < 4; ++i) {
      af[i]  = *(const bf16x8*)(sA + (wr + i * 16 + m16) * 32 + quad * 8);
      bfr[i] = *(const bf16x8*)(sB + (wc + i * 16 + m16) * 32 + quad * 8);
    }
#pragma unroll
    for (int i = 0; i < 4; ++i)
#pragma unroll
      for (int j = 0; j < 4; ++j)
        acc[i][j] = __builtin_amdgcn_mfma_f32_16x16x32_bf16(af[i], bfr[j], acc[i][j], 0, 0, 0);
  }

  // C/D layout: col = lane&15, row = (lane>>4)*4 + r  [verified m89/m91]
#pragma unroll
  for (int i = 0; i < 4; ++i) {
#pragma unroll
    for (int r = 0; r < 4; ++r) {
      int row = row0 + wr + i * 16 + quad * 4 + r;
#pragma unroll
      for (int j = 0; j < 4; ++j) {
        int col = col0 + wc + j * 16 + m16;
        float v = acc[i][j][r];
        if (OUT_BF16) ((ushort*)Cv)[(size_t)row * N + col] = f2bf(v);
        else          ((float*)Cv)[(size_t)row * N + col] = v;
      }
    }
  }
}

// ---------------- fused hilbert attention, MFMA version ----------------
// one workgroup (256 thr = 4 waves) per (b,h,s,nb): 64 q x 64 dilated keys x 64 d
__global__ __launch_bounds__(256) void attn_kernel(const ushort* __restrict__ qkv,
                                                   const int* __restrict__ hmap,
                                                   ushort* __restrict__ out) {
  __shared__ __align__(16) ushort sQ[64 * 72];    // [q][d] bf16, pad 8
  __shared__ __align__(16) ushort sK[64 * 72];    // [t][d] bf16
  __shared__ __align__(16) ushort sVT[64 * 72];   // [d][t] bf16 (transposed for B-operand)
  __shared__ __align__(16) ushort sWb[64 * 72];   // [q][t] bf16 weights
  __shared__ float sCmax[4 * 64];
  __shared__ float sDen[64];

  const int bid = blockIdx.x;
  const int nb = bid & 1;
  const int s  = (bid >> 1) & 31;
  const int h  = (bid >> 6) & 15;
  const int b  = bid >> 10;
  const int tid = threadIdx.x;
  const int lane = tid & 63;
  const int wave = tid >> 6;
  const int m16 = lane & 15;
  const int quad = lane >> 4;

  // ---- stage Q, K (raw bf16 copies), V transposed ----
  {
    const int r = tid >> 2;           // 0..63
    const int c = (tid & 3) * 16;     // 16 d-elems
    const int gq = b * MM + hmap[s * SEGSZ + nb * 64 + r];
    const int gk = b * MM + hmap[s * SEGSZ + 2 * r];
    const ushort* qrow = qkv + (size_t)gq * QKVC + h * HDIM + c;
    const ushort* krow = qkv + (size_t)gk * QKVC + DM + h * HDIM + c;
    const ushort* vrow = qkv + (size_t)gk * QKVC + 2 * DM + h * HDIM + c;
    *(uint4*)(sQ + r * 72 + c)     = ((const uint4*)qrow)[0];
    *(uint4*)(sQ + r * 72 + c + 8) = ((const uint4*)qrow)[1];
    *(uint4*)(sK + r * 72 + c)     = ((const uint4*)krow)[0];
    *(uint4*)(sK + r * 72 + c + 8) = ((const uint4*)krow)[1];
    ushort vv[16];
    *(uint4*)(vv)     = ((const uint4*)vrow)[0];
    *(uint4*)(vv + 8) = ((const uint4*)vrow)[1];
#pragma unroll
    for (int u = 0; u < 16; ++u) sVT[(c + u) * 72 + r] = vv[u];   // t = r
  }
  __syncthreads();

  // ---- scores S = Q K^T (raw), then *SCALE; wave w owns query rows w*16..+15 ----
  f32x4 sc[4];
  {
    bf16x8 aq[2], bk[4][2];
#pragma unroll
    for (int ks = 0; ks < 2; ++ks) {
      aq[ks] = *(const bf16x8*)(sQ + (wave * 16 + m16) * 72 + ks * 32 + quad * 8);
#pragma unroll
      for (int j = 0; j < 4; ++j)
        bk[j][ks] = *(const bf16x8*)(sK + (j * 16 + m16) * 72 + ks * 32 + quad * 8);
    }
#pragma unroll
    for (int j = 0; j < 4; ++j) {
      f32x4 a = {};
      a = __builtin_amdgcn_mfma_f32_16x16x32_bf16(aq[0], bk[j][0], a, 0, 0, 0);
      a = __builtin_amdgcn_mfma_f32_16x16x32_bf16(aq[1], bk[j][1], a, 0, 0, 0);
      sc[j] = a * 0.125f;    // HD^-0.5
    }
  }

  // ---- per-KEY max over the 64-query block (faithful quirk) ----
  // C layout: row q = wave*16+quad*4+r, col t = j*16+m16
#pragma unroll
  for (int j = 0; j < 4; ++j) {
    float m = fmaxf(fmaxf(sc[j][0], sc[j][1]), fmaxf(sc[j][2], sc[j][3]));
    m = fmaxf(m, __shfl_xor(m, 16));   // across quads (same col)
    m = fmaxf(m, __shfl_xor(m, 32));
    if (quad == 0) sCmax[wave * 64 + j * 16 + m16] = m;
  }
  __syncthreads();

  // ---- w = exp(s - c); row sums ----
  float w[4][4];
  float part[4] = {0.f, 0.f, 0.f, 0.f};
#pragma unroll
  for (int j = 0; j < 4; ++j) {
    const int col = j * 16 + m16;
    float c0 = fmaxf(fmaxf(sCmax[col], sCmax[64 + col]),
                     fmaxf(sCmax[128 + col], sCmax[192 + col]));
#pragma unroll
    for (int r = 0; r < 4; ++r) {
      float ww = __expf(sc[j][r] - c0);
      w[j][r] = ww;
      part[r] += ww;
    }
  }
#pragma unroll
  for (int r = 0; r < 4; ++r) {
    float p = part[r];
    p += __shfl_xor(p, 1); p += __shfl_xor(p, 2);
    p += __shfl_xor(p, 4); p += __shfl_xor(p, 8);
    part[r] = p;
  }
  if (m16 == 0) {
#pragma unroll
    for (int r = 0; r < 4; ++r) sDen[wave * 16 + quad * 4 + r] = part[r];
  }
  // W -> LDS as bf16 (A-operand layout round-trip, m120 pattern)
#pragma unroll
  for (int j = 0; j < 4; ++j)
#pragma unroll
    for (int r = 0; r < 4; ++r)
      sWb[(wave * 16 + quad * 4 + r) * 72 + j * 16 + m16] = f2bf(w[j][r]);
  __syncthreads();

  // ---- O = W @ V via MFMA (A = W[q][t], B^T = V^T[d][t]) ----
  f32x4 o[4] = {};
  {
    bf16x8 aw[2], bv[4][2];
#pragma unroll
    for (int ks = 0; ks < 2; ++ks) {
      aw[ks] = *(const bf16x8*)(sWb + (wave * 16 + m16) * 72 + ks * 32 + quad * 8);
#pragma unroll
      for (int j = 0; j < 4; ++j)
        bv[j][ks] = *(const bf16x8*)(sVT + (j * 16 + m16) * 72 + ks * 32 + quad * 8);
    }
#pragma unroll
    for (int j = 0; j < 4; ++j) {
      o[j] = __builtin_amdgcn_mfma_f32_16x16x32_bf16(aw[0], bv[j][0], o[j], 0, 0, 0);
      o[j] = __builtin_amdgcn_mfma_f32_16x16x32_bf16(aw[1], bv[j][1], o[j], 0, 0, 0);
    }
  }

  // ---- divide by den, store at LINEAR positions ----
  float rden[4];
#pragma unroll
  for (int r = 0; r < 4; ++r)
    rden[r] = 1.0f / (1e-10f + sDen[wave * 16 + quad * 4 + r]);
  const size_t orow0 = (size_t)(b * MM + s * SEGSZ + nb * 64 + wave * 16 + quad * 4);
#pragma unroll
  for (int r = 0; r < 4; ++r) {
    ushort* op = out + (orow0 + r) * DM + h * HDIM + m16;
#pragma unroll
    for (int j = 0; j < 4; ++j)
      op[j * 16] = f2bf(o[j][r] * rden[r]);
  }
}

// ---------------- launch ----------------
extern "C" void kernel_launch(void* const* d_in, const int* in_sizes, int n_in,
                              void* d_out, int out_size, void* d_ws, size_t ws_size,
                              hipStream_t stream) {
  const float* x    = (const float*)d_in[0];
  const float* wqkv = (const float*)d_in[1];
  const float* wout = (const float*)d_in[2];
  const int*   hmap = (const int*)d_in[3];
  float* outp = (float*)d_out;

  ushort* xbf    = (ushort*)d_ws;                          // ROWS*DM
  ushort* wqkvbf = xbf + (size_t)ROWS * DM;                // QKVC*DM
  ushort* woutbf = wqkvbf + (size_t)QKVC * DM;             // DM*DM
  ushort* qkv    = woutbf + (size_t)DM * DM;               // ROWS*QKVC
  ushort* attn   = qkv + (size_t)ROWS * QKVC;              // ROWS*DM

  const int nx = ROWS * DM, nw1 = QKVC * DM, nw2 = DM * DM;
  cvt_bf16<<<(nx / 4 + 255) / 256, 256, 0, stream>>>((const float4*)x, (ushort4*)xbf, nx / 4);
  cvt_bf16<<<(nw1 / 4 + 255) / 256, 256, 0, stream>>>((const float4*)wqkv, (ushort4*)wqkvbf, nw1 / 4);
  cvt_bf16<<<(nw2 / 4 + 255) / 256, 256, 0, stream>>>((const float4*)wout, (ushort4*)woutbf, nw2 / 4);

  // qkv = x @ Wqkv^T
  gemm_nt<1><<<dim3(ROWS / 128, QKVC / 128), 256, 0, stream>>>(xbf, wqkvbf, qkv, ROWS, QKVC, DM);

  // fused hilbert attention (MFMA)
  attn_kernel<<<BB * NH * NSEG * 2, 256, 0, stream>>>(qkv, hmap, attn);

  // out = attn @ Wout^T (fp32 out)
  gemm_nt<0><<<dim3(ROWS / 128, DM / 128), 256, 0, stream>>>(attn, woutbf, outp, ROWS, DM, DM);
}

// Round 3
// 339.731 us; speedup vs baseline: 1.2128x; 1.0248x over previous
//
#include <hip/hip_runtime.h>
#include <hip/hip_bf16.h>

// Problem constants (B=4, M=4096, DM=1024, H=16, HD=64, SEG=128, DIL=2, BLOCK_M=64)
#define BB 4
#define MM 4096
#define DM 1024
#define NH 16
#define HDIM 64
#define SEGSZ 128
#define NSEG 32
#define ROWS (BB*MM)     // 16384
#define QKVC (3*DM)      // 3072

typedef __attribute__((ext_vector_type(8))) short bf16x8;
typedef __attribute__((ext_vector_type(4))) float f32x4;

__device__ inline unsigned short f2bf(float f) {
  __hip_bfloat16 h = __float2bfloat16(f);
  return *reinterpret_cast<unsigned short*>(&h);
}

// async global->LDS, 16B per lane; LDS dest = wave-uniform base + lane*16
__device__ __forceinline__ void gld16(const ushort* g, ushort* l) {
  __builtin_amdgcn_global_load_lds(
      (const __attribute__((address_space(1))) unsigned int*)g,
      (__attribute__((address_space(3))) unsigned int*)l,
      16, 0, 0);
}

// ---------------- fp32 -> bf16 convert ----------------
__global__ __launch_bounds__(256) void cvt_bf16(const float4* __restrict__ in,
                                                ushort4* __restrict__ out, int n4) {
  int i = blockIdx.x * 256 + threadIdx.x;
  if (i >= n4) return;
  float4 v = in[i];
  ushort4 o;
  o.x = f2bf(v.x); o.y = f2bf(v.y); o.z = f2bf(v.z); o.w = f2bf(v.w);
  out[i] = o;
}

// ---------------- NT GEMM (m97 structure + XOR-swizzled LDS) ----------------
// C[m][n] = sum_k A[m,k]*B[n,k]. 128x128 tile, BK=32, 256 threads.
// LDS linear chunk (r,c) holds GLOBAL chunk (r, c^(r&3)); fragment reads invert
// the XOR -> full 32-bank spread (2-way only = free) with no padding.
template<int OUT_BF16>
__global__ __launch_bounds__(256) void gemm_nt(const ushort* __restrict__ A,
                                               const ushort* __restrict__ B,
                                               void* __restrict__ Cv,
                                               int M, int N, int K) {
  __shared__ __align__(16) ushort sA[128 * 32];
  __shared__ __align__(16) ushort sB[128 * 32];
  const int tid  = threadIdx.x;
  const int lane = tid & 63;
  const int wave = tid >> 6;
  const int row0 = blockIdx.x * 128;
  const int col0 = blockIdx.y * 128;
  const int wr = (wave >> 1) * 64;
  const int wc = (wave & 1) * 64;
  const int m16 = lane & 15;
  const int quad = lane >> 4;

  f32x4 acc[4][4] = {};

  // chunk = 16B = 8 bf16; tile = 512 chunks; linear chunk L -> row L>>2, col-slot L&3
  const int ch0 = wave * 64 + lane;
  const int ch1 = 256 + wave * 64 + lane;
  const int r0 = ch0 >> 2, k0 = ((ch0 & 3) ^ (r0 & 3)) * 8;   // swizzled global col
  const int r1 = ch1 >> 2, k1 = ((ch1 & 3) ^ (r1 & 3)) * 8;

  const ushort* Ab = A + (size_t)row0 * K;
  const ushort* Bb = B + (size_t)col0 * K;
  ushort* sA0 = sA + wave * 512;
  ushort* sA1 = sA + 2048 + wave * 512;
  ushort* sB0 = sB + wave * 512;
  ushort* sB1 = sB + 2048 + wave * 512;

  // fragment read: logical k-chunk = quad, physical slot = quad ^ (row&3)
  const int sw = (quad ^ (m16 & 3)) * 8;

  for (int kt = 0; kt < K; kt += 32) {
    __syncthreads();
    gld16(Ab + (size_t)r0 * K + kt + k0, sA0);
    gld16(Ab + (size_t)r1 * K + kt + k1, sA1);
    gld16(Bb + (size_t)r0 * K + kt + k0, sB0);
    gld16(Bb + (size_t)r1 * K + kt + k1, sB1);
    __syncthreads();

    bf16x8 af[4], bfr[4];
#pragma unroll
    for (int i = 0; i < 4; ++i) {
      af[i]  = *(const bf16x8*)(sA + (wr + i * 16 + m16) * 32 + sw);
      bfr[i] = *(const bf16x8*)(sB + (wc + i * 16 + m16) * 32 + sw);
    }
#pragma unroll
    for (int i = 0; i < 4; ++i)
#pragma unroll
      for (int j = 0; j < 4; ++j)
        acc[i][j] = __builtin_amdgcn_mfma_f32_16x16x32_bf16(af[i], bfr[j], acc[i][j], 0, 0, 0);
  }

  // C/D layout: col = lane&15, row = (lane>>4)*4 + r  [verified m89/m91]
#pragma unroll
  for (int i = 0; i < 4; ++i) {
#pragma unroll
    for (int r = 0; r < 4; ++r) {
      int row = row0 + wr + i * 16 + quad * 4 + r;
#pragma unroll
      for (int j = 0; j < 4; ++j) {
        int col = col0 + wc + j * 16 + m16;
        float v = acc[i][j][r];
        if (OUT_BF16) ((ushort*)Cv)[(size_t)row * N + col] = f2bf(v);
        else          ((float*)Cv)[(size_t)row * N + col] = v;
      }
    }
  }
}

// ---------------- fused hilbert attention (nb-merged, MFMA) ----------------
// one workgroup (256 thr = 4 waves) per (b,h,s): 128 queries x 64 dilated keys.
// waves 0,1 own query rows 0..63 (nb=0); waves 2,3 own rows 64..127 (nb=1).
// Per-key max is taken per 64-query block (faithful quirk).
__global__ __launch_bounds__(256) void attn_kernel(const ushort* __restrict__ qkv,
                                                   const int* __restrict__ hmap,
                                                   ushort* __restrict__ out) {
  __shared__ __align__(16) ushort sQW[128 * 72];  // Q [q][d] bf16; reused for W [q][t]
  __shared__ __align__(16) ushort sK[64 * 72];    // [t][d] bf16
  __shared__ __align__(16) ushort sVT[64 * 72];   // [d][t] bf16
  __shared__ float sCmaxW[4 * 64];                // per-wave partial col max
  __shared__ float sDen[128];

  const int bid = blockIdx.x;
  const int s  = bid & 31;
  const int h  = (bid >> 5) & 15;
  const int b  = bid >> 9;
  const int tid = threadIdx.x;
  const int lane = tid & 63;
  const int wave = tid >> 6;
  const int m16 = lane & 15;
  const int quad = lane >> 4;
  const int qb = wave * 32;          // this wave's first query row
  const int hb = wave >> 1;          // which 64-query block (nb)

  // ---- stage Q (128 rows), K + V^T (64 rows) ----
  {
    const int qr = tid >> 1;                 // 0..127
    const int qc = (tid & 1) * 32;           // 32 d-elems = 4 chunks
    const int gq = b * MM + hmap[s * SEGSZ + qr];
    const ushort* qrow = qkv + (size_t)gq * QKVC + h * HDIM + qc;
    uint4 q0 = ((const uint4*)qrow)[0], q1 = ((const uint4*)qrow)[1];
    uint4 q2 = ((const uint4*)qrow)[2], q3 = ((const uint4*)qrow)[3];
    *(uint4*)(sQW + qr * 72 + qc)      = q0;
    *(uint4*)(sQW + qr * 72 + qc + 8)  = q1;
    *(uint4*)(sQW + qr * 72 + qc + 16) = q2;
    *(uint4*)(sQW + qr * 72 + qc + 24) = q3;

    const int r = tid >> 2;                  // 0..63
    const int c = (tid & 3) * 16;
    const int gk = b * MM + hmap[s * SEGSZ + 2 * r];
    const ushort* krow = qkv + (size_t)gk * QKVC + DM + h * HDIM + c;
    const ushort* vrow = qkv + (size_t)gk * QKVC + 2 * DM + h * HDIM + c;
    *(uint4*)(sK + r * 72 + c)     = ((const uint4*)krow)[0];
    *(uint4*)(sK + r * 72 + c + 8) = ((const uint4*)krow)[1];
    ushort vv[16];
    *(uint4*)(vv)     = ((const uint4*)vrow)[0];
    *(uint4*)(vv + 8) = ((const uint4*)vrow)[1];
#pragma unroll
    for (int u = 0; u < 16; ++u) sVT[(c + u) * 72 + r] = vv[u];   // t = r
  }
  __syncthreads();

  // ---- S = (Q K^T) * SCALE ; wave handles rows qb..qb+31 via 2 row-blocks ----
  f32x4 sc[2][4];
  {
    bf16x8 aq[2][2], bk[4][2];
#pragma unroll
    for (int ks = 0; ks < 2; ++ks) {
#pragma unroll
      for (int ib = 0; ib < 2; ++ib)
        aq[ib][ks] = *(const bf16x8*)(sQW + (qb + ib * 16 + m16) * 72 + ks * 32 + quad * 8);
#pragma unroll
      for (int j = 0; j < 4; ++j)
        bk[j][ks] = *(const bf16x8*)(sK + (j * 16 + m16) * 72 + ks * 32 + quad * 8);
    }
#pragma unroll
    for (int ib = 0; ib < 2; ++ib)
#pragma unroll
      for (int j = 0; j < 4; ++j) {
        f32x4 a = {};
        a = __builtin_amdgcn_mfma_f32_16x16x32_bf16(aq[ib][0], bk[j][0], a, 0, 0, 0);
        a = __builtin_amdgcn_mfma_f32_16x16x32_bf16(aq[ib][1], bk[j][1], a, 0, 0, 0);
        sc[ib][j] = a * 0.125f;    // HD^-0.5
      }
  }

  // ---- per-key max over this wave's 32 rows, then combine wave pairs ----
#pragma unroll
  for (int j = 0; j < 4; ++j) {
    float m = -1e30f;
#pragma unroll
    for (int ib = 0; ib < 2; ++ib)
#pragma unroll
      for (int r = 0; r < 4; ++r) m = fmaxf(m, sc[ib][j][r]);
    m = fmaxf(m, __shfl_xor(m, 16));
    m = fmaxf(m, __shfl_xor(m, 32));
    if (quad == 0) sCmaxW[wave * 64 + j * 16 + m16] = m;
  }
  __syncthreads();

  // ---- w = exp(s - c); per-row sums; W -> LDS (alias over dead Q) ----
  {
    float part[2][4] = {};
#pragma unroll
    for (int j = 0; j < 4; ++j) {
      const int col = j * 16 + m16;
      float c0 = fmaxf(sCmaxW[hb * 128 + col], sCmaxW[hb * 128 + 64 + col]);
#pragma unroll
      for (int ib = 0; ib < 2; ++ib)
#pragma unroll
        for (int r = 0; r < 4; ++r) {
          float ww = __expf(sc[ib][j][r] - c0);
          sc[ib][j][r] = ww;
          part[ib][r] += ww;
        }
    }
#pragma unroll
    for (int ib = 0; ib < 2; ++ib)
#pragma unroll
      for (int r = 0; r < 4; ++r) {
        float p = part[ib][r];
        p += __shfl_xor(p, 1); p += __shfl_xor(p, 2);
        p += __shfl_xor(p, 4); p += __shfl_xor(p, 8);
        if (m16 == 0) sDen[qb + ib * 16 + quad * 4 + r] = p;
      }
    // note: all waves finished reading Q (S stage) before the barrier above
#pragma unroll
    for (int ib = 0; ib < 2; ++ib)
#pragma unroll
      for (int j = 0; j < 4; ++j)
#pragma unroll
        for (int r = 0; r < 4; ++r)
          sQW[(qb + ib * 16 + quad * 4 + r) * 72 + j * 16 + m16] = f2bf(sc[ib][j][r]);
  }
  __syncthreads();

  // ---- O = W @ V via MFMA (A = W[q][t], B = V^T[d][t]) ----
  f32x4 o[2][4] = {};
  {
    bf16x8 aw[2][2], bv[4][2];
#pragma unroll
    for (int ks = 0; ks < 2; ++ks) {
#pragma unroll
      for (int ib = 0; ib < 2; ++ib)
        aw[ib][ks] = *(const bf16x8*)(sQW + (qb + ib * 16 + m16) * 72 + ks * 32 + quad * 8);
#pragma unroll
      for (int j = 0; j < 4; ++j)
        bv[j][ks] = *(const bf16x8*)(sVT + (j * 16 + m16) * 72 + ks * 32 + quad * 8);
    }
#pragma unroll
    for (int ib = 0; ib < 2; ++ib)
#pragma unroll
      for (int j = 0; j < 4; ++j) {
        o[ib][j] = __builtin_amdgcn_mfma_f32_16x16x32_bf16(aw[ib][0], bv[j][0], o[ib][j], 0, 0, 0);
        o[ib][j] = __builtin_amdgcn_mfma_f32_16x16x32_bf16(aw[ib][1], bv[j][1], o[ib][j], 0, 0, 0);
      }
  }

  // ---- divide by den, store at LINEAR positions ----
#pragma unroll
  for (int ib = 0; ib < 2; ++ib) {
#pragma unroll
    for (int r = 0; r < 4; ++r) {
      const int lrow = qb + ib * 16 + quad * 4 + r;
      float rd = 1.0f / (1e-10f + sDen[lrow]);
      ushort* op = out + (size_t)(b * MM + s * SEGSZ + lrow) * DM + h * HDIM + m16;
#pragma unroll
      for (int j = 0; j < 4; ++j)
        op[j * 16] = f2bf(o[ib][j][r] * rd);
    }
  }
}

// ---------------- launch ----------------
extern "C" void kernel_launch(void* const* d_in, const int* in_sizes, int n_in,
                              void* d_out, int out_size, void* d_ws, size_t ws_size,
                              hipStream_t stream) {
  const float* x    = (const float*)d_in[0];
  const float* wqkv = (const float*)d_in[1];
  const float* wout = (const float*)d_in[2];
  const int*   hmap = (const int*)d_in[3];
  float* outp = (float*)d_out;

  ushort* xbf    = (ushort*)d_ws;                          // ROWS*DM
  ushort* wqkvbf = xbf + (size_t)ROWS * DM;                // QKVC*DM
  ushort* woutbf = wqkvbf + (size_t)QKVC * DM;             // DM*DM
  ushort* qkv    = woutbf + (size_t)DM * DM;               // ROWS*QKVC
  ushort* attn   = qkv + (size_t)ROWS * QKVC;              // ROWS*DM

  const int nx = ROWS * DM, nw1 = QKVC * DM, nw2 = DM * DM;
  cvt_bf16<<<(nx / 4 + 255) / 256, 256, 0, stream>>>((const float4*)x, (ushort4*)xbf, nx / 4);
  cvt_bf16<<<(nw1 / 4 + 255) / 256, 256, 0, stream>>>((const float4*)wqkv, (ushort4*)wqkvbf, nw1 / 4);
  cvt_bf16<<<(nw2 / 4 + 255) / 256, 256, 0, stream>>>((const float4*)wout, (ushort4*)woutbf, nw2 / 4);

  // qkv = x @ Wqkv^T
  gemm_nt<1><<<dim3(ROWS / 128, QKVC / 128), 256, 0, stream>>>(xbf, wqkvbf, qkv, ROWS, QKVC, DM);

  // fused hilbert attention (nb-merged)
  attn_kernel<<<BB * NH * NSEG, 256, 0, stream>>>(qkv, hmap, attn);

  // out = attn @ Wout^T (fp32 out)
  gemm_nt<0><<<dim3(ROWS / 128, DM / 128), 256, 0, stream>>>(attn, woutbf, outp, ROWS, DM, DM);
}

// Round 4
// 316.150 us; speedup vs baseline: 1.3033x; 1.0746x over previous
//
#include <hip/hip_runtime.h>
#include <hip/hip_bf16.h>

// Problem constants (B=4, M=4096, DM=1024, H=16, HD=64, SEG=128, DIL=2, BLOCK_M=64)
#define BB 4
#define MM 4096
#define DM 1024
#define NH 16
#define HDIM 64
#define SEGSZ 128
#define NSEG 32
#define ROWS (BB*MM)     // 16384
#define QKVC (3*DM)      // 3072
#define KVROWS (BB*MM/2) // 8192 compact key rows
#define KVLD 2048        // K | V stacked columns

typedef __attribute__((ext_vector_type(8))) short bf16x8;
typedef __attribute__((ext_vector_type(4))) float f32x4;

__device__ inline unsigned short f2bf(float f) {
  __hip_bfloat16 h = __float2bfloat16(f);
  return *reinterpret_cast<unsigned short*>(&h);
}

// async global->LDS, 16B per lane; LDS dest = wave-uniform base + lane*16
__device__ __forceinline__ void gld16(const ushort* g, ushort* l) {
  __builtin_amdgcn_global_load_lds(
      (const __attribute__((address_space(1))) unsigned int*)g,
      (__attribute__((address_space(3))) unsigned int*)l,
      16, 0, 0);
}

// ---------------- fp32 -> bf16 convert ----------------
__global__ __launch_bounds__(256) void cvt_bf16(const float4* __restrict__ in,
                                                ushort4* __restrict__ out, int n4) {
  int i = blockIdx.x * 256 + threadIdx.x;
  if (i >= n4) return;
  float4 v = in[i];
  ushort4 o;
  o.x = f2bf(v.x); o.y = f2bf(v.y); o.z = f2bf(v.z); o.w = f2bf(v.w);
  out[i] = o;
}

// ---------------- NT GEMM (m97 structure), optional gathered A rows ----------------
// C[m][n] = sum_k A[arow(m),k]*B[n,k]. 128x128 tile, BK=32, 256 threads.
// GATHER: 0 = linear rows, 1 = hilbert Q rows, 2 = compact dilated key rows.
template<int OUT_BF16, int GATHER>
__global__ __launch_bounds__(256) void gemm_nt(const ushort* __restrict__ A,
                                               const ushort* __restrict__ B,
                                               void* __restrict__ Cv,
                                               const int* __restrict__ hmap,
                                               int M, int N, int K) {
  __shared__ __align__(16) ushort sA[128 * 32];   // unpadded: global_load_lds dest
  __shared__ __align__(16) ushort sB[128 * 32];
  __shared__ int sRow[128];
  const int tid  = threadIdx.x;
  const int lane = tid & 63;
  const int wave = tid >> 6;
  const int row0 = blockIdx.x * 128;
  const int col0 = blockIdx.y * 128;
  const int wr = (wave >> 1) * 64;
  const int wc = (wave & 1) * 64;
  const int m16 = lane & 15;
  const int quad = lane >> 4;

  if (GATHER != 0) {
    if (tid < 128) {
      int m = row0 + tid;
      int xrow;
      if (GATHER == 1) {                 // Q: hilbert-ordered output
        int b = m >> 12, p = m & 4095;
        xrow = (b << 12) + hmap[p];
      } else {                           // KV: compact dilated key rows
        int b = m >> 11, idx = m & 2047;
        int s = idx >> 6, t = idx & 63;
        xrow = (b << 12) + hmap[s * SEGSZ + 2 * t];
      }
      sRow[tid] = xrow;
    }
    __syncthreads();
  }

  f32x4 acc[4][4] = {};

  // chunk = 16B = 8 bf16; tile = 512 chunks
  const int ch0 = wave * 64 + lane;
  const int ch1 = 256 + wave * 64 + lane;
  const int r0 = ch0 >> 2, k0 = (ch0 & 3) * 8;
  const int r1 = ch1 >> 2, k1 = (ch1 & 3) * 8;

  const ushort *pa0, *pa1;
  if (GATHER != 0) {
    pa0 = A + (size_t)sRow[r0] * K + k0;
    pa1 = A + (size_t)sRow[r1] * K + k1;
  } else {
    pa0 = A + (size_t)(row0 + r0) * K + k0;
    pa1 = A + (size_t)(row0 + r1) * K + k1;
  }
  const ushort* pb0 = B + (size_t)(col0 + r0) * K + k0;
  const ushort* pb1 = B + (size_t)(col0 + r1) * K + k1;

  ushort* sA0 = sA + wave * 512;
  ushort* sA1 = sA + 2048 + wave * 512;
  ushort* sB0 = sB + wave * 512;
  ushort* sB1 = sB + 2048 + wave * 512;

  for (int kt = 0; kt < K; kt += 32) {
    __syncthreads();
    gld16(pa0 + kt, sA0);
    gld16(pa1 + kt, sA1);
    gld16(pb0 + kt, sB0);
    gld16(pb1 + kt, sB1);
    __syncthreads();

    bf16x8 af[4], bfr[4];
#pragma unroll
    for (int i = 0; i < 4; ++i) {
      af[i]  = *(const bf16x8*)(sA + (wr + i * 16 + m16) * 32 + quad * 8);
      bfr[i] = *(const bf16x8*)(sB + (wc + i * 16 + m16) * 32 + quad * 8);
    }
#pragma unroll
    for (int i = 0; i < 4; ++i)
#pragma unroll
      for (int j = 0; j < 4; ++j)
        acc[i][j] = __builtin_amdgcn_mfma_f32_16x16x32_bf16(af[i], bfr[j], acc[i][j], 0, 0, 0);
  }

  // C/D layout: col = lane&15, row = (lane>>4)*4 + r  [verified m89/m91]
#pragma unroll
  for (int i = 0; i < 4; ++i) {
#pragma unroll
    for (int r = 0; r < 4; ++r) {
      int row = row0 + wr + i * 16 + quad * 4 + r;
#pragma unroll
      for (int j = 0; j < 4; ++j) {
        int col = col0 + wc + j * 16 + m16;
        float v = acc[i][j][r];
        if (OUT_BF16) ((ushort*)Cv)[(size_t)row * N + col] = f2bf(v);
        else          ((float*)Cv)[(size_t)row * N + col] = v;
      }
    }
  }
}

// ---------------- fused hilbert attention (compact inputs, MFMA) ----------------
// one workgroup (256 thr = 4 waves) per (b,h,s): 128 queries x 64 dilated keys.
// Inputs are pre-gathered: qh [16384][1024] hilbert-ordered; kv [8192][2048]
// compact key rows (K cols 0..1023, V cols 1024..2047). No hmap here.
__global__ __launch_bounds__(256) void attn_kernel(const ushort* __restrict__ qh,
                                                   const ushort* __restrict__ kv,
                                                   ushort* __restrict__ out) {
  __shared__ __align__(16) ushort sQW[128 * 72];  // Q [q][d]; reused for W [q][t]
  __shared__ __align__(16) ushort sK[64 * 72];    // [t][d]
  __shared__ __align__(16) ushort sVT[64 * 72];   // [d][t]
  __shared__ float sCmaxW[4 * 64];
  __shared__ float sDen[128];

  const int bid = blockIdx.x;
  const int s  = bid & 31;
  const int h  = (bid >> 5) & 15;
  const int b  = bid >> 9;
  const int tid = threadIdx.x;
  const int lane = tid & 63;
  const int wave = tid >> 6;
  const int m16 = lane & 15;
  const int quad = lane >> 4;
  const int qb = wave * 32;
  const int hb = wave >> 1;

  // ---- stage Q (128 rows), K + V^T (64 rows) — all coalesced, no gather ----
  {
    const int qr = tid >> 1;                 // 0..127
    const int qc = (tid & 1) * 32;
    const ushort* qrow = qh + (size_t)(b * MM + s * SEGSZ + qr) * DM + h * HDIM + qc;
    *(uint4*)(sQW + qr * 72 + qc)      = ((const uint4*)qrow)[0];
    *(uint4*)(sQW + qr * 72 + qc + 8)  = ((const uint4*)qrow)[1];
    *(uint4*)(sQW + qr * 72 + qc + 16) = ((const uint4*)qrow)[2];
    *(uint4*)(sQW + qr * 72 + qc + 24) = ((const uint4*)qrow)[3];

    const int r = tid >> 2;                  // 0..63
    const int c = (tid & 3) * 16;
    const ushort* krow = kv + (size_t)(b * (MM/2) + s * 64 + r) * KVLD + h * HDIM + c;
    const ushort* vrow = krow + DM;          // V stacked at col offset 1024
    *(uint4*)(sK + r * 72 + c)     = ((const uint4*)krow)[0];
    *(uint4*)(sK + r * 72 + c + 8) = ((const uint4*)krow)[1];
    ushort vv[16];
    *(uint4*)(vv)     = ((const uint4*)vrow)[0];
    *(uint4*)(vv + 8) = ((const uint4*)vrow)[1];
#pragma unroll
    for (int u = 0; u < 16; ++u) sVT[(c + u) * 72 + r] = vv[u];   // t = r
  }
  __syncthreads();

  // ---- S = (Q K^T) * SCALE ----
  f32x4 sc[2][4];
  {
    bf16x8 aq[2][2], bk[4][2];
#pragma unroll
    for (int ks = 0; ks < 2; ++ks) {
#pragma unroll
      for (int ib = 0; ib < 2; ++ib)
        aq[ib][ks] = *(const bf16x8*)(sQW + (qb + ib * 16 + m16) * 72 + ks * 32 + quad * 8);
#pragma unroll
      for (int j = 0; j < 4; ++j)
        bk[j][ks] = *(const bf16x8*)(sK + (j * 16 + m16) * 72 + ks * 32 + quad * 8);
    }
#pragma unroll
    for (int ib = 0; ib < 2; ++ib)
#pragma unroll
      for (int j = 0; j < 4; ++j) {
        f32x4 a = {};
        a = __builtin_amdgcn_mfma_f32_16x16x32_bf16(aq[ib][0], bk[j][0], a, 0, 0, 0);
        a = __builtin_amdgcn_mfma_f32_16x16x32_bf16(aq[ib][1], bk[j][1], a, 0, 0, 0);
        sc[ib][j] = a * 0.125f;    // HD^-0.5
      }
  }

  // ---- per-key max per 64-query block (faithful quirk) ----
#pragma unroll
  for (int j = 0; j < 4; ++j) {
    float m = -1e30f;
#pragma unroll
    for (int ib = 0; ib < 2; ++ib)
#pragma unroll
      for (int r = 0; r < 4; ++r) m = fmaxf(m, sc[ib][j][r]);
    m = fmaxf(m, __shfl_xor(m, 16));
    m = fmaxf(m, __shfl_xor(m, 32));
    if (quad == 0) sCmaxW[wave * 64 + j * 16 + m16] = m;
  }
  __syncthreads();

  // ---- w = exp(s - c); per-row sums; W -> LDS (alias over dead Q) ----
  {
    float part[2][4] = {};
#pragma unroll
    for (int j = 0; j < 4; ++j) {
      const int col = j * 16 + m16;
      float c0 = fmaxf(sCmaxW[hb * 128 + col], sCmaxW[hb * 128 + 64 + col]);
#pragma unroll
      for (int ib = 0; ib < 2; ++ib)
#pragma unroll
        for (int r = 0; r < 4; ++r) {
          float ww = __expf(sc[ib][j][r] - c0);
          sc[ib][j][r] = ww;
          part[ib][r] += ww;
        }
    }
#pragma unroll
    for (int ib = 0; ib < 2; ++ib)
#pragma unroll
      for (int r = 0; r < 4; ++r) {
        float p = part[ib][r];
        p += __shfl_xor(p, 1); p += __shfl_xor(p, 2);
        p += __shfl_xor(p, 4); p += __shfl_xor(p, 8);
        if (m16 == 0) sDen[qb + ib * 16 + quad * 4 + r] = p;
      }
#pragma unroll
    for (int ib = 0; ib < 2; ++ib)
#pragma unroll
      for (int j = 0; j < 4; ++j)
#pragma unroll
        for (int r = 0; r < 4; ++r)
          sQW[(qb + ib * 16 + quad * 4 + r) * 72 + j * 16 + m16] = f2bf(sc[ib][j][r]);
  }
  __syncthreads();

  // ---- O = W @ V via MFMA (A = W[q][t], B = V^T[d][t]) ----
  f32x4 o[2][4] = {};
  {
    bf16x8 aw[2][2], bv[4][2];
#pragma unroll
    for (int ks = 0; ks < 2; ++ks) {
#pragma unroll
      for (int ib = 0; ib < 2; ++ib)
        aw[ib][ks] = *(const bf16x8*)(sQW + (qb + ib * 16 + m16) * 72 + ks * 32 + quad * 8);
#pragma unroll
      for (int j = 0; j < 4; ++j)
        bv[j][ks] = *(const bf16x8*)(sVT + (j * 16 + m16) * 72 + ks * 32 + quad * 8);
    }
#pragma unroll
    for (int ib = 0; ib < 2; ++ib)
#pragma unroll
      for (int j = 0; j < 4; ++j) {
        o[ib][j] = __builtin_amdgcn_mfma_f32_16x16x32_bf16(aw[ib][0], bv[j][0], o[ib][j], 0, 0, 0);
        o[ib][j] = __builtin_amdgcn_mfma_f32_16x16x32_bf16(aw[ib][1], bv[j][1], o[ib][j], 0, 0, 0);
      }
  }

  // ---- divide by den, store at LINEAR positions ----
#pragma unroll
  for (int ib = 0; ib < 2; ++ib) {
#pragma unroll
    for (int r = 0; r < 4; ++r) {
      const int lrow = qb + ib * 16 + quad * 4 + r;
      float rd = 1.0f / (1e-10f + sDen[lrow]);
      ushort* op = out + (size_t)(b * MM + s * SEGSZ + lrow) * DM + h * HDIM + m16;
#pragma unroll
      for (int j = 0; j < 4; ++j)
        op[j * 16] = f2bf(o[ib][j][r] * rd);
    }
  }
}

// ---------------- launch ----------------
extern "C" void kernel_launch(void* const* d_in, const int* in_sizes, int n_in,
                              void* d_out, int out_size, void* d_ws, size_t ws_size,
                              hipStream_t stream) {
  const float* x    = (const float*)d_in[0];
  const float* wqkv = (const float*)d_in[1];
  const float* wout = (const float*)d_in[2];
  const int*   hmap = (const int*)d_in[3];
  float* outp = (float*)d_out;

  ushort* xbf    = (ushort*)d_ws;                          // ROWS*DM
  ushort* wqkvbf = xbf + (size_t)ROWS * DM;                // QKVC*DM
  ushort* woutbf = wqkvbf + (size_t)QKVC * DM;             // DM*DM
  ushort* qhb    = woutbf + (size_t)DM * DM;               // ROWS*DM (hilbert-ordered Q)
  ushort* kvb    = qhb + (size_t)ROWS * DM;                // KVROWS*KVLD (compact K|V)
  ushort* attn   = kvb + (size_t)KVROWS * KVLD;            // ROWS*DM

  const int nx = ROWS * DM, nw1 = QKVC * DM, nw2 = DM * DM;
  cvt_bf16<<<(nx / 4 + 255) / 256, 256, 0, stream>>>((const float4*)x, (ushort4*)xbf, nx / 4);
  cvt_bf16<<<(nw1 / 4 + 255) / 256, 256, 0, stream>>>((const float4*)wqkv, (ushort4*)wqkvbf, nw1 / 4);
  cvt_bf16<<<(nw2 / 4 + 255) / 256, 256, 0, stream>>>((const float4*)wout, (ushort4*)woutbf, nw2 / 4);

  // Q = x[hmap] @ Wq^T (hilbert-ordered rows)
  gemm_nt<1, 1><<<dim3(ROWS / 128, DM / 128), 256, 0, stream>>>(
      xbf, wqkvbf, qhb, hmap, ROWS, DM, DM);

  // KV = x[dilated keys] @ [Wk;Wv]^T (compact rows, 2048 cols)
  gemm_nt<1, 2><<<dim3(KVROWS / 128, KVLD / 128), 256, 0, stream>>>(
      xbf, wqkvbf + (size_t)DM * DM, kvb, hmap, KVROWS, KVLD, DM);

  // fused hilbert attention (compact, coalesced)
  attn_kernel<<<BB * NH * NSEG, 256, 0, stream>>>(qhb, kvb, attn);

  // out = attn @ Wout^T (fp32 out)
  gemm_nt<0, 0><<<dim3(ROWS / 128, DM / 128), 256, 0, stream>>>(
      attn, woutbf, outp, hmap, ROWS, DM, DM);
}

// Round 5
// 297.242 us; speedup vs baseline: 1.3862x; 1.0636x over previous
//
#include <hip/hip_runtime.h>
#include <hip/hip_bf16.h>

// Problem constants (B=4, M=4096, DM=1024, H=16, HD=64, SEG=128, DIL=2, BLOCK_M=64)
#define BB 4
#define MM 4096
#define DM 1024
#define NH 16
#define HDIM 64
#define SEGSZ 128
#define NSEG 32
#define ROWS (BB*MM)     // 16384
#define QKVC (3*DM)      // 3072
#define KVROWS (BB*MM/2) // 8192 compact key rows
#define KVLD 2048        // K | V stacked columns
#define NX4  (ROWS*DM/4)     // 4194304
#define NW14 (QKVC*DM/4)     // 786432
#define NW24 (DM*DM/4)       // 262144

typedef __attribute__((ext_vector_type(8))) short bf16x8;
typedef __attribute__((ext_vector_type(4))) float f32x4;

__device__ inline unsigned short f2bf(float f) {
  __hip_bfloat16 h = __float2bfloat16(f);
  return *reinterpret_cast<unsigned short*>(&h);
}

// async global->LDS, 16B per lane; LDS dest = wave-uniform base + lane*16
__device__ __forceinline__ void gld16(const ushort* g, ushort* l) {
  __builtin_amdgcn_global_load_lds(
      (const __attribute__((address_space(1))) unsigned int*)g,
      (__attribute__((address_space(3))) unsigned int*)l,
      16, 0, 0);
}

// ---------------- fused fp32 -> bf16 convert (x | Wqkv | Wout) ----------------
__global__ __launch_bounds__(256) void cvt_all(const float4* __restrict__ x,
                                               const float4* __restrict__ w1,
                                               const float4* __restrict__ w2,
                                               ushort4* __restrict__ xo,
                                               ushort4* __restrict__ w1o,
                                               ushort4* __restrict__ w2o) {
  int i = blockIdx.x * 256 + threadIdx.x;
  const float4* src; ushort4* dst; int off;
  if (i < NX4)              { src = x;  dst = xo;  off = i; }
  else if (i < NX4 + NW14)  { src = w1; dst = w1o; off = i - NX4; }
  else                      { src = w2; dst = w2o; off = i - NX4 - NW14; }
  float4 v = src[off];
  ushort4 o;
  o.x = f2bf(v.x); o.y = f2bf(v.y); o.z = f2bf(v.z); o.w = f2bf(v.w);
  dst[off] = o;
}

// ---------------- merged Q + KV projection GEMM (one 2048-block dispatch) ----------------
// blocks 0..1023:  Q  = x[hilbert rows] @ Wq^T   -> qhb [16384][1024], 128x128 tiles
// blocks 1024..2047: KV = x[dilated rows] @ [Wk;Wv]^T -> kvb [8192][2048], 128x128 tiles
__global__ __launch_bounds__(256) void gemm_qkv(const ushort* __restrict__ xbf,
                                                const ushort* __restrict__ wqkv,
                                                ushort* __restrict__ qhb,
                                                ushort* __restrict__ kvb,
                                                const int* __restrict__ hmap) {
  __shared__ __align__(16) ushort sA[128 * 32];   // unpadded: global_load_lds dest
  __shared__ __align__(16) ushort sB[128 * 32];
  __shared__ int sRow[128];
  const int blk = blockIdx.x;
  const int tid = threadIdx.x;
  const int lane = tid & 63;
  const int wave = tid >> 6;
  const int m16 = lane & 15;
  const int quad = lane >> 4;

  const ushort* Bmat; ushort* C; int row0, col0, N;
  if (blk < 1024) {
    row0 = (blk >> 3) * 128; col0 = (blk & 7) * 128;
    Bmat = wqkv; C = qhb; N = DM;
  } else {
    int j = blk - 1024;
    row0 = (j >> 4) * 128; col0 = (j & 15) * 128;
    Bmat = wqkv + (size_t)DM * DM; C = kvb; N = KVLD;
  }

  if (tid < 128) {
    int m = row0 + tid, xrow;
    if (blk < 1024) {                    // hilbert-ordered Q rows
      int b = m >> 12, p = m & 4095;
      xrow = (b << 12) + hmap[p];
    } else {                             // compact dilated key rows
      int b = m >> 11, idx = m & 2047;
      int s = idx >> 6, t = idx & 63;
      xrow = (b << 12) + hmap[s * SEGSZ + 2 * t];
    }
    sRow[tid] = xrow;
  }
  __syncthreads();

  f32x4 acc[4][4] = {};
  const int wr = (wave >> 1) * 64;
  const int wc = (wave & 1) * 64;

  const int ch0 = wave * 64 + lane;
  const int ch1 = 256 + wave * 64 + lane;
  const int r0 = ch0 >> 2, k0 = (ch0 & 3) * 8;
  const int r1 = ch1 >> 2, k1 = (ch1 & 3) * 8;

  const ushort* pa0 = xbf + (size_t)sRow[r0] * DM + k0;
  const ushort* pa1 = xbf + (size_t)sRow[r1] * DM + k1;
  const ushort* pb0 = Bmat + (size_t)(col0 + r0) * DM + k0;
  const ushort* pb1 = Bmat + (size_t)(col0 + r1) * DM + k1;
  ushort* sA0 = sA + wave * 512;
  ushort* sA1 = sA + 2048 + wave * 512;
  ushort* sB0 = sB + wave * 512;
  ushort* sB1 = sB + 2048 + wave * 512;

  for (int kt = 0; kt < DM; kt += 32) {
    __syncthreads();
    gld16(pa0 + kt, sA0);
    gld16(pa1 + kt, sA1);
    gld16(pb0 + kt, sB0);
    gld16(pb1 + kt, sB1);
    __syncthreads();

    bf16x8 af[4], bfr[4];
#pragma unroll
    for (int i = 0; i < 4; ++i) {
      af[i]  = *(const bf16x8*)(sA + (wr + i * 16 + m16) * 32 + quad * 8);
      bfr[i] = *(const bf16x8*)(sB + (wc + i * 16 + m16) * 32 + quad * 8);
    }
#pragma unroll
    for (int i = 0; i < 4; ++i)
#pragma unroll
      for (int j = 0; j < 4; ++j)
        acc[i][j] = __builtin_amdgcn_mfma_f32_16x16x32_bf16(af[i], bfr[j], acc[i][j], 0, 0, 0);
  }

  // C/D layout: col = lane&15, row = (lane>>4)*4 + r
#pragma unroll
  for (int i = 0; i < 4; ++i)
#pragma unroll
    for (int r = 0; r < 4; ++r) {
      int row = row0 + wr + i * 16 + quad * 4 + r;
#pragma unroll
      for (int j = 0; j < 4; ++j)
        C[(size_t)row * N + col0 + wc + j * 16 + m16] = f2bf(acc[i][j][r]);
    }
}

// ---------------- out-projection GEMM: 128x64 tiles, 2048 blocks, fp32 out ----------------
// out[m][n] = sum_k attn[m,k] * Wout[n,k]
__global__ __launch_bounds__(256) void gemm_out(const ushort* __restrict__ A,
                                                const ushort* __restrict__ Bmat,
                                                float* __restrict__ C) {
  __shared__ __align__(16) ushort sA[128 * 32];   // 8 KB
  __shared__ __align__(16) ushort sB[64 * 32];    // 4 KB
  const int blk = blockIdx.x;                     // 128 row-tiles x 16 col-tiles
  const int row0 = (blk >> 4) * 128;
  const int col0 = (blk & 15) * 64;
  const int tid = threadIdx.x;
  const int lane = tid & 63;
  const int wave = tid >> 6;
  const int m16 = lane & 15;
  const int quad = lane >> 4;
  const int wr = (wave >> 1) * 64;
  const int wc = (wave & 1) * 32;

  f32x4 acc[4][2] = {};

  const int ch0 = wave * 64 + lane;          // A chunks 0..255, B chunks 0..255
  const int ch1 = 256 + wave * 64 + lane;    // A chunks 256..511
  const int ra0 = ch0 >> 2, ka0 = (ch0 & 3) * 8;
  const int ra1 = ch1 >> 2, ka1 = (ch1 & 3) * 8;

  const ushort* pa0 = A + (size_t)(row0 + ra0) * DM + ka0;
  const ushort* pa1 = A + (size_t)(row0 + ra1) * DM + ka1;
  const ushort* pb0 = Bmat + (size_t)(col0 + ra0) * DM + ka0;   // ra0 < 64
  ushort* lA0 = sA + wave * 512;
  ushort* lA1 = sA + 2048 + wave * 512;
  ushort* lB0 = sB + wave * 512;

  for (int kt = 0; kt < DM; kt += 32) {
    __syncthreads();
    gld16(pa0 + kt, lA0);
    gld16(pa1 + kt, lA1);
    gld16(pb0 + kt, lB0);
    __syncthreads();

    bf16x8 af[4], bfr[2];
#pragma unroll
    for (int i = 0; i < 4; ++i)
      af[i] = *(const bf16x8*)(sA + (wr + i * 16 + m16) * 32 + quad * 8);
#pragma unroll
    for (int j = 0; j < 2; ++j)
      bfr[j] = *(const bf16x8*)(sB + (wc + j * 16 + m16) * 32 + quad * 8);
#pragma unroll
    for (int i = 0; i < 4; ++i)
#pragma unroll
      for (int j = 0; j < 2; ++j)
        acc[i][j] = __builtin_amdgcn_mfma_f32_16x16x32_bf16(af[i], bfr[j], acc[i][j], 0, 0, 0);
  }

#pragma unroll
  for (int i = 0; i < 4; ++i)
#pragma unroll
    for (int r = 0; r < 4; ++r) {
      int row = row0 + wr + i * 16 + quad * 4 + r;
#pragma unroll
      for (int j = 0; j < 2; ++j)
        C[(size_t)row * DM + col0 + wc + j * 16 + m16] = acc[i][j][r];
    }
}

// ---------------- fused hilbert attention (compact inputs, MFMA) ----------------
// one workgroup (256 thr = 4 waves) per (b,h,s): 128 queries x 64 dilated keys.
__global__ __launch_bounds__(256) void attn_kernel(const ushort* __restrict__ qh,
                                                   const ushort* __restrict__ kv,
                                                   ushort* __restrict__ out) {
  __shared__ __align__(16) ushort sQW[128 * 72];  // Q [q][d]; reused for W [q][t]
  __shared__ __align__(16) ushort sK[64 * 72];    // [t][d]
  __shared__ __align__(16) ushort sVT[64 * 72];   // [d][t]
  __shared__ float sCmaxW[4 * 64];
  __shared__ float sDen[128];

  const int bid = blockIdx.x;
  const int s  = bid & 31;
  const int h  = (bid >> 5) & 15;
  const int b  = bid >> 9;
  const int tid = threadIdx.x;
  const int lane = tid & 63;
  const int wave = tid >> 6;
  const int m16 = lane & 15;
  const int quad = lane >> 4;
  const int qb = wave * 32;
  const int hb = wave >> 1;

  // ---- stage Q (128 rows), K + V^T (64 rows) — all coalesced ----
  {
    const int qr = tid >> 1;
    const int qc = (tid & 1) * 32;
    const ushort* qrow = qh + (size_t)(b * MM + s * SEGSZ + qr) * DM + h * HDIM + qc;
    *(uint4*)(sQW + qr * 72 + qc)      = ((const uint4*)qrow)[0];
    *(uint4*)(sQW + qr * 72 + qc + 8)  = ((const uint4*)qrow)[1];
    *(uint4*)(sQW + qr * 72 + qc + 16) = ((const uint4*)qrow)[2];
    *(uint4*)(sQW + qr * 72 + qc + 24) = ((const uint4*)qrow)[3];

    const int r = tid >> 2;
    const int c = (tid & 3) * 16;
    const ushort* krow = kv + (size_t)(b * (MM/2) + s * 64 + r) * KVLD + h * HDIM + c;
    const ushort* vrow = krow + DM;
    *(uint4*)(sK + r * 72 + c)     = ((const uint4*)krow)[0];
    *(uint4*)(sK + r * 72 + c + 8) = ((const uint4*)krow)[1];
    ushort vv[16];
    *(uint4*)(vv)     = ((const uint4*)vrow)[0];
    *(uint4*)(vv + 8) = ((const uint4*)vrow)[1];
#pragma unroll
    for (int u = 0; u < 16; ++u) sVT[(c + u) * 72 + r] = vv[u];
  }
  __syncthreads();

  // ---- S = (Q K^T) * SCALE ----
  f32x4 sc[2][4];
  {
    bf16x8 aq[2][2], bk[4][2];
#pragma unroll
    for (int ks = 0; ks < 2; ++ks) {
#pragma unroll
      for (int ib = 0; ib < 2; ++ib)
        aq[ib][ks] = *(const bf16x8*)(sQW + (qb + ib * 16 + m16) * 72 + ks * 32 + quad * 8);
#pragma unroll
      for (int j = 0; j < 4; ++j)
        bk[j][ks] = *(const bf16x8*)(sK + (j * 16 + m16) * 72 + ks * 32 + quad * 8);
    }
#pragma unroll
    for (int ib = 0; ib < 2; ++ib)
#pragma unroll
      for (int j = 0; j < 4; ++j) {
        f32x4 a = {};
        a = __builtin_amdgcn_mfma_f32_16x16x32_bf16(aq[ib][0], bk[j][0], a, 0, 0, 0);
        a = __builtin_amdgcn_mfma_f32_16x16x32_bf16(aq[ib][1], bk[j][1], a, 0, 0, 0);
        sc[ib][j] = a * 0.125f;
      }
  }

  // ---- per-key max per 64-query block (faithful quirk) ----
#pragma unroll
  for (int j = 0; j < 4; ++j) {
    float m = -1e30f;
#pragma unroll
    for (int ib = 0; ib < 2; ++ib)
#pragma unroll
      for (int r = 0; r < 4; ++r) m = fmaxf(m, sc[ib][j][r]);
    m = fmaxf(m, __shfl_xor(m, 16));
    m = fmaxf(m, __shfl_xor(m, 32));
    if (quad == 0) sCmaxW[wave * 64 + j * 16 + m16] = m;
  }
  __syncthreads();

  // ---- w = exp(s - c); per-row sums; W -> LDS (alias over dead Q) ----
  {
    float part[2][4] = {};
#pragma unroll
    for (int j = 0; j < 4; ++j) {
      const int col = j * 16 + m16;
      float c0 = fmaxf(sCmaxW[hb * 128 + col], sCmaxW[hb * 128 + 64 + col]);
#pragma unroll
      for (int ib = 0; ib < 2; ++ib)
#pragma unroll
        for (int r = 0; r < 4; ++r) {
          float ww = __expf(sc[ib][j][r] - c0);
          sc[ib][j][r] = ww;
          part[ib][r] += ww;
        }
    }
#pragma unroll
    for (int ib = 0; ib < 2; ++ib)
#pragma unroll
      for (int r = 0; r < 4; ++r) {
        float p = part[ib][r];
        p += __shfl_xor(p, 1); p += __shfl_xor(p, 2);
        p += __shfl_xor(p, 4); p += __shfl_xor(p, 8);
        if (m16 == 0) sDen[qb + ib * 16 + quad * 4 + r] = p;
      }
#pragma unroll
    for (int ib = 0; ib < 2; ++ib)
#pragma unroll
      for (int j = 0; j < 4; ++j)
#pragma unroll
        for (int r = 0; r < 4; ++r)
          sQW[(qb + ib * 16 + quad * 4 + r) * 72 + j * 16 + m16] = f2bf(sc[ib][j][r]);
  }
  __syncthreads();

  // ---- O = W @ V via MFMA ----
  f32x4 o[2][4] = {};
  {
    bf16x8 aw[2][2], bv[4][2];
#pragma unroll
    for (int ks = 0; ks < 2; ++ks) {
#pragma unroll
      for (int ib = 0; ib < 2; ++ib)
        aw[ib][ks] = *(const bf16x8*)(sQW + (qb + ib * 16 + m16) * 72 + ks * 32 + quad * 8);
#pragma unroll
      for (int j = 0; j < 4; ++j)
        bv[j][ks] = *(const bf16x8*)(sVT + (j * 16 + m16) * 72 + ks * 32 + quad * 8);
    }
#pragma unroll
    for (int ib = 0; ib < 2; ++ib)
#pragma unroll
      for (int j = 0; j < 4; ++j) {
        o[ib][j] = __builtin_amdgcn_mfma_f32_16x16x32_bf16(aw[ib][0], bv[j][0], o[ib][j], 0, 0, 0);
        o[ib][j] = __builtin_amdgcn_mfma_f32_16x16x32_bf16(aw[ib][1], bv[j][1], o[ib][j], 0, 0, 0);
      }
  }

  // ---- divide by den, store at LINEAR positions ----
#pragma unroll
  for (int ib = 0; ib < 2; ++ib)
#pragma unroll
    for (int r = 0; r < 4; ++r) {
      const int lrow = qb + ib * 16 + quad * 4 + r;
      float rd = 1.0f / (1e-10f + sDen[lrow]);
      ushort* op = out + (size_t)(b * MM + s * SEGSZ + lrow) * DM + h * HDIM + m16;
#pragma unroll
      for (int j = 0; j < 4; ++j)
        op[j * 16] = f2bf(o[ib][j][r] * rd);
    }
}

// ---------------- launch ----------------
extern "C" void kernel_launch(void* const* d_in, const int* in_sizes, int n_in,
                              void* d_out, int out_size, void* d_ws, size_t ws_size,
                              hipStream_t stream) {
  const float* x    = (const float*)d_in[0];
  const float* wqkv = (const float*)d_in[1];
  const float* wout = (const float*)d_in[2];
  const int*   hmap = (const int*)d_in[3];
  float* outp = (float*)d_out;

  ushort* xbf    = (ushort*)d_ws;                          // ROWS*DM
  ushort* wqkvbf = xbf + (size_t)ROWS * DM;                // QKVC*DM
  ushort* woutbf = wqkvbf + (size_t)QKVC * DM;             // DM*DM
  ushort* qhb    = woutbf + (size_t)DM * DM;               // ROWS*DM (hilbert-ordered Q)
  ushort* kvb    = qhb + (size_t)ROWS * DM;                // KVROWS*KVLD (compact K|V)
  ushort* attn   = kvb + (size_t)KVROWS * KVLD;            // ROWS*DM

  cvt_all<<<(NX4 + NW14 + NW24 + 255) / 256, 256, 0, stream>>>(
      (const float4*)x, (const float4*)wqkv, (const float4*)wout,
      (ushort4*)xbf, (ushort4*)wqkvbf, (ushort4*)woutbf);

  // Q + KV projections in one dispatch (2048 blocks)
  gemm_qkv<<<2048, 256, 0, stream>>>(xbf, wqkvbf, qhb, kvb, hmap);

  // fused hilbert attention (compact, coalesced)
  attn_kernel<<<BB * NH * NSEG, 256, 0, stream>>>(qhb, kvb, attn);

  // out = attn @ Wout^T (fp32 out, 128x64 tiles, 2048 blocks)
  gemm_out<<<2048, 256, 0, stream>>>(attn, woutbf, outp);
}